// Round 16
// baseline (198.264 us; speedup 1.0000x reference)
//
#include <hip/hip_runtime.h>

typedef unsigned short u16;
typedef unsigned int u32;
typedef __bf16 bf16x8 __attribute__((ext_vector_type(8)));
typedef float f32x4 __attribute__((ext_vector_type(4)));
typedef u16 u16x4 __attribute__((ext_vector_type(4)));
typedef u16 u16x8 __attribute__((ext_vector_type(8)));

#define MFMA16x16x32(a, b, c) __builtin_amdgcn_mfma_f32_16x16x32_bf16((a), (b), (c), 0, 0, 0)

static constexpr int kB = 4;
static constexpr int kC = 256;
static constexpr int kN = 4096;     // H*W
static constexpr int kHeads = 4;    // per batch
static constexpr int kD = 64;       // head dim
static constexpr float kScale = 0.35355339059327373f;   // 64^-0.25 (K side)
static constexpr float kScaleQ = 0.51006971545f;        // 64^-0.25 * log2(e) (Q side)

__device__ __forceinline__ u16 f2bf(float f) {
  union { float f; u32 i; } v; v.f = f;
  return (u16)((v.i + 0x7fffu + ((v.i >> 16) & 1u)) >> 16);
}
__device__ __forceinline__ bf16x8 ldb8(const u16* p) {
  return *reinterpret_cast<const bf16x8*>(p);
}
// r21 (validated): raw v_exp_f32 (2^x); OCML exp2f carries fixup VALU.
__device__ __forceinline__ float fast_exp2(float x) {
#if __has_builtin(__builtin_amdgcn_exp2f)
  return __builtin_amdgcn_exp2f(x);
#else
  float r;
  asm("v_exp_f32 %0, %1" : "=v"(r) : "v"(x));
  return r;
#endif
}

// ---------------------------------------------------------------------------
// GroupNorm (validated r4) + r29: weight conversion folded in as grid row
// g==32 (saves one launch). Writes bf16 transposed xnT[b][t][c].
// ---------------------------------------------------------------------------
__global__ __launch_bounds__(1024) void gn_kernel(const float* __restrict__ x,
                                                  const float* __restrict__ gnw,
                                                  const float* __restrict__ gnb,
                                                  u16* __restrict__ xnT,
                                                  const float* __restrict__ w1,
                                                  u16* __restrict__ o1, int n1,
                                                  const float* __restrict__ w2,
                                                  u16* __restrict__ o2) {
  const int g = blockIdx.x, b = blockIdx.y;
  const int tid = threadIdx.x;
  if (g == 32) {   // conversion blocks: 4 x 1024 threads x 64 iters = 262144
    const int base = b * 65536;
    for (int i = tid; i < 65536; i += 1024) {
      const int idx = base + i;
      if (idx < n1) o1[idx] = f2bf(w1[idx]);
      else o2[idx - n1] = f2bf(w2[idx - n1]);
    }
    return;
  }
  const float* xb = x + b * (kC * kN) + g * 8 * kN;
  float vals[4][8];
  float s = 0.f, ss = 0.f;
#pragma unroll
  for (int kk = 0; kk < 4; ++kk) {
    const int t = tid + kk * 1024;
#pragma unroll
    for (int c = 0; c < 8; ++c) {
      const float v_ = xb[c * kN + t];
      vals[kk][c] = v_;
      s += v_; ss += v_ * v_;
    }
  }
#pragma unroll
  for (int off = 32; off > 0; off >>= 1) {
    s += __shfl_down(s, off);
    ss += __shfl_down(ss, off);
  }
  __shared__ float rbuf[32];
  const int wid = tid >> 6, lane = tid & 63;
  if (lane == 0) { rbuf[wid] = s; rbuf[16 + wid] = ss; }
  __syncthreads();
  if (tid < 64) {
    float s2 = (lane < 16) ? rbuf[lane] : 0.f;
    float ss2 = (lane < 16) ? rbuf[16 + lane] : 0.f;
#pragma unroll
    for (int off = 8; off > 0; off >>= 1) {
      s2 += __shfl_down(s2, off);
      ss2 += __shfl_down(ss2, off);
    }
    if (lane == 0) { rbuf[0] = s2; rbuf[1] = ss2; }
  }
  __syncthreads();
  const float inv_n = 1.f / 32768.f;
  const float mu = rbuf[0] * inv_n;
  const float var = rbuf[1] * inv_n - mu * mu;
  const float rs = rsqrtf(var + 1e-5f);
  float wv[8], bv[8];
#pragma unroll
  for (int c = 0; c < 8; ++c) {
    const float wgt = gnw[g * 8 + c] * rs;
    wv[c] = wgt;
    bv[c] = gnb[g * 8 + c] - mu * wgt;
  }
  u16* ob = xnT + b * (kN * kC) + g * 8;
#pragma unroll
  for (int kk = 0; kk < 4; ++kk) {
    const int t = tid + kk * 1024;
    u16x8 pk;
#pragma unroll
    for (int c = 0; c < 8; ++c) pk[c] = f2bf(vals[kk][c] * wv[c] + bv[c]);
    *reinterpret_cast<u16x8*>(ob + t * kC) = pk;
  }
}

// ---------------------------------------------------------------------------
// QKV GEMM. r22 (validated): LDS staging + XOR swizzle. r28: M-loop (B panel
// staged once per block; neutral on time, less HBM).
// Epilogue: r19 V slot-permutation m = 8*(col>>2)+4*(nt&1)+(col&3) within
// each 32-col block matches attn's in-register P order; Q side folds log2e.
// ---------------------------------------------------------------------------
__global__ __launch_bounds__(256) void qkv_gemm(const u16* __restrict__ qkvw,
                                                const float* __restrict__ qkvb,
                                                const u16* __restrict__ xnT,
                                                u16* __restrict__ qt,
                                                u16* __restrict__ kt,
                                                u16* __restrict__ vv) {
  const int nblk = blockIdx.x, mseg = blockIdx.y, b = blockIdx.z;
  const int tid = threadIdx.x;
  const int w = tid >> 6, l = tid & 63, quad = l >> 4, col = l & 15;
  const int n0 = nblk * 64;
  __shared__ __align__(16) u16 als[64 * 256];   // 32 KiB (A tile, reused)
  __shared__ __align__(16) u16 bls[64 * 256];   // 32 KiB (B panel, once)
  {
    const u16* bsrc = xnT + (size_t)b * (kN * kC) + (size_t)n0 * kC;
#pragma unroll
    for (int p = 0; p < 8; ++p) {
      const int li = p * 256 + tid;        // [0,2048)
      const int row = li >> 5, ch = li & 31;
      const int sw = (ch ^ (row & 7)) * 8;
      *reinterpret_cast<bf16x8*>(&bls[row * 256 + sw]) = ldb8(bsrc + li * 8);
    }
  }
  const int kx = col & 7;
  for (int msub = 0; msub < 4; ++msub) {
    const int mblk = mseg * 4 + msub;
    const int m0 = mblk * 64 + w * 16;
    {
      const u16* asrc = qkvw + (size_t)(mblk * 64) * kC;
#pragma unroll
      for (int p = 0; p < 8; ++p) {
        const int li = p * 256 + tid;
        const int row = li >> 5, ch = li & 31;
        const int sw = (ch ^ (row & 7)) * 8;
        *reinterpret_cast<bf16x8*>(&als[row * 256 + sw]) = ldb8(asrc + li * 8);
      }
    }
    __syncthreads();
    f32x4 acc[4] = {{0,0,0,0},{0,0,0,0},{0,0,0,0},{0,0,0,0}};
    const u16* arow = &als[(w * 16 + col) * 256];
#pragma unroll
    for (int ks = 0; ks < 8; ++ks) {
      const bf16x8 af = ldb8(arow + (((ks * 4 + quad) ^ kx)) * 8);
#pragma unroll
      for (int nt = 0; nt < 4; ++nt) {
        const bf16x8 bfr =
            ldb8(&bls[(nt * 16 + col) * 256 + (((ks * 4 + quad) ^ kx)) * 8]);
        acc[nt] = MFMA16x16x32(af, bfr, acc[nt]);
      }
    }
    const int o_base = m0 + quad * 4;
    const int head = o_base / 192;
    const int rr = o_base % 192;
    const int bh = b * kHeads + head;
    const int seg = rr >> 6;
    const int c0 = rr & 63;
    float bias[4];
#pragma unroll
    for (int r = 0; r < 4; ++r) bias[r] = qkvb[o_base + r];
    const float sc = (seg == 0) ? kScaleQ : kScale;
#pragma unroll
    for (int nt = 0; nt < 4; ++nt) {
      const int t = n0 + nt * 16 + col;
      if (seg == 2) {
        const int tp = n0 + (nt >> 1) * 32 + 8 * (col >> 2) + 4 * (nt & 1) + (col & 3);
#pragma unroll
        for (int r = 0; r < 4; ++r)
          vv[bh * (kD * kN) + (c0 + r) * kN + tp] = f2bf(acc[nt][r] + bias[r]);
      } else {
        u16* dst = (seg == 0 ? qt : kt) + bh * (kN * kD) + t * kD + c0;
        u16x4 pk;
#pragma unroll
        for (int r = 0; r < 4; ++r) pk[r] = f2bf((acc[nt][r] + bias[r]) * sc);
        *reinterpret_cast<u16x4*>(dst) = pk;
      }
    }
    __syncthreads();   // protect als before next m-tile overwrites it
  }
}

// ---------------------------------------------------------------------------
// Flash attention, UNSPLIT. Validated ladder: r20 staging, r21 fast_exp2,
// r24 fused combine, r27 4-phase, r28 setprio (+4.5%).
// r29: XCD-aware block remap (T1). FETCH was 69.7MB vs 25MB ideal: the 32
// tblk-blocks sharing each bh's K/V round-robin across the 8 private L2s,
// so every XCD re-fetches nearly every bh's K/V. Remap bid so each XCD owns
// exactly 2 bh (2MB < 4MB L2): xcd=bid&7, j=bid>>3, bh=(xcd<<1)|(j>>5),
// tblk=j&31 (bijective over 512; speed-only, G16-safe).
// ---------------------------------------------------------------------------
__global__ __launch_bounds__(512, 4) void attn_split(const u16* __restrict__ qt,
                                                     const u16* __restrict__ kt,
                                                     const u16* __restrict__ vv,
                                                     u16* __restrict__ ht) {
  const int bid = blockIdx.x;
  const int xcd = bid & 7, j = bid >> 3;
  const int bh = (xcd << 1) | (j >> 5);
  const int tblk = j & 31;
  const int tid = threadIdx.x;
  const int w = tid >> 6, l = tid & 63, quad = l >> 4, col = l & 15;
  const int t0 = tblk * 128 + w * 16;          // 8 waves x 16 q-rows
  const u16* qb = qt + bh * (kN * kD);
  const u16* kb = kt + bh * (kN * kD);
  const u16* vb = vv + bh * (kD * kN);
  bf16x8 qf0, qf1;
  qf0 = ldb8(qb + (t0 + col) * kD + quad * 8);
  qf1 = ldb8(qb + (t0 + col) * kD + 32 + quad * 8);
  u16x8 ones_u;
#pragma unroll
  for (int i = 0; i < 8; ++i) ones_u[i] = 0x3f80;  // bf16 1.0
  const bf16x8 onesf = *reinterpret_cast<bf16x8*>(&ones_u);
  f32x4 oacc[4];
  f32x4 lacc = {0, 0, 0, 0};
#pragma unroll
  for (int ct = 0; ct < 4; ++ct) oacc[ct] = f32x4{0, 0, 0, 0};

  __shared__ __align__(16) u16 kls[2][4][32][64];   // 32 KiB: [buf][half]
  __shared__ __align__(16) u16 vls[2][4][32][64];   // 32 KiB
  constexpr int NIT = kN / 128;                      // 32
  constexpr int BUFSTRIDE = 4 * 32 * 64;             // 8192 u16

  // --- staging roles: 512 threads, 2 K-chunks + 2 V-chunks of 16B each ---
  const int r6 = tid >> 3, c3 = tid & 7;             // K chunk 0: row r6
  const u16* ksrc = kb + (size_t)r6 * kD + c3 * 8;   // chunk 1: +64 rows
  u16* kdst = &kls[0][r6 >> 5][r6 & 31][(c3 ^ (r6 & 7)) * 8];
  // V chunk 0: id=tid (half vh, row vr, chunk vc3); chunk 1: id+512 (half+2)
  const int vh = tid >> 8, vcc = tid & 255, vr = vcc >> 3, vc3 = vcc & 7;
  const int sa = vc3 >> 2, sq = vc3 & 3;
  const u16* vsrc = vb + (size_t)(2 * vr + sa) * kN + vh * 32 + sq * 8;
  u16* vdst = &vls[0][vh][vr][(((sa << 2) | sq) ^ (vr & 7)) * 8];

  // prologue: load tile 0 (4 chunks)
  bf16x8 kstg0 = ldb8(ksrc);
  bf16x8 kstg1 = ldb8(ksrc + (size_t)64 * kD);
  bf16x8 vstg0 = ldb8(vsrc);
  bf16x8 vstg1 = ldb8(vsrc + 64);

#pragma unroll 2
  for (int it = 0; it < NIT; ++it) {
    const int cb = (it & 1) * BUFSTRIDE;
    *reinterpret_cast<bf16x8*>(kdst + cb) = kstg0;
    *reinterpret_cast<bf16x8*>(kdst + cb + 2 * 2048) = kstg1;
    *reinterpret_cast<bf16x8*>(vdst + cb) = vstg0;
    *reinterpret_cast<bf16x8*>(vdst + cb + 2 * 2048) = vstg1;
    __syncthreads();
    if (it + 1 < NIT) {
      const size_t sb = (size_t)(it + 1) * 128;
      kstg0 = ldb8(ksrc + sb * kD);
      kstg1 = ldb8(ksrc + (sb + 64) * kD);
      vstg0 = ldb8(vsrc + sb);
      vstg1 = ldb8(vsrc + sb + 64);
    }
    const int kx = (col & 7) * 8;
    const int vslot = (((col & 1) << 2) | quad) ^ (col >> 1);
#pragma unroll
    for (int h = 0; h < 4; ++h) {
      const u16* kl = &kls[0][0][0][0] + cb + h * 2048;
      const u16* vl = &vls[0][0][0][0] + cb + h * 2048;
      const bf16x8 k00 = ldb8(kl + col * 64 + ((quad * 8) ^ kx));
      const bf16x8 k01 = ldb8(kl + col * 64 + ((32 + quad * 8) ^ kx));
      const bf16x8 k10 = ldb8(kl + (col + 16) * 64 + ((quad * 8) ^ kx));
      const bf16x8 k11 = ldb8(kl + (col + 16) * 64 + ((32 + quad * 8) ^ kx));
      bf16x8 vf[4];
#pragma unroll
      for (int ct = 0; ct < 4; ++ct)
        vf[ct] = ldb8(vl + (ct * 8 + (col >> 1)) * 64 + vslot * 8);
      f32x4 sa0 = {0, 0, 0, 0}, sa1 = {0, 0, 0, 0};
      __builtin_amdgcn_s_setprio(1);
      sa0 = MFMA16x16x32(k00, qf0, sa0);
      sa0 = MFMA16x16x32(k01, qf1, sa0);
      sa1 = MFMA16x16x32(k10, qf0, sa1);
      sa1 = MFMA16x16x32(k11, qf1, sa1);
      __builtin_amdgcn_s_setprio(0);
      const u32 e00 = __float_as_uint(fast_exp2(sa0[0]));
      const u32 e01 = __float_as_uint(fast_exp2(sa0[1]));
      const u32 e02 = __float_as_uint(fast_exp2(sa0[2]));
      const u32 e03 = __float_as_uint(fast_exp2(sa0[3]));
      const u32 e10 = __float_as_uint(fast_exp2(sa1[0]));
      const u32 e11 = __float_as_uint(fast_exp2(sa1[1]));
      const u32 e12 = __float_as_uint(fast_exp2(sa1[2]));
      const u32 e13 = __float_as_uint(fast_exp2(sa1[3]));
      union { u32 wd[4]; bf16x8 v; } pa;
      pa.wd[0] = __builtin_amdgcn_perm(e01, e00, 0x07060302u);
      pa.wd[1] = __builtin_amdgcn_perm(e03, e02, 0x07060302u);
      pa.wd[2] = __builtin_amdgcn_perm(e11, e10, 0x07060302u);
      pa.wd[3] = __builtin_amdgcn_perm(e13, e12, 0x07060302u);
      __builtin_amdgcn_s_setprio(1);
#pragma unroll
      for (int ct = 0; ct < 4; ++ct)
        oacc[ct] = MFMA16x16x32(pa.v, vf[ct], oacc[ct]);
      lacc = MFMA16x16x32(pa.v, onesf, lacc);
      __builtin_amdgcn_s_setprio(0);
    }
  }
  // epilogue: divide by l (every col holds l[q]) and write ht bf16 directly
  const int b = bh >> 2, head = bh & 3;
  u16* hb = ht + (size_t)b * (kN * kC) + head * kD;
#pragma unroll
  for (int r = 0; r < 4; ++r) {
    const int t = t0 + quad * 4 + r;
    const float inv = 1.f / lacc[r];
#pragma unroll
    for (int ct = 0; ct < 4; ++ct)
      hb[(size_t)t * kC + ct * 16 + col] = f2bf(oacc[ct][r] * inv);
  }
}

// ---------------------------------------------------------------------------
// Proj GEMM + bias + residual: out fp32 (B,C,H,W). r22 (validated): LDS
// staging (A=projw 64x256 tile, B=ht 64x256 tile, coalesced + swizzled).
// ---------------------------------------------------------------------------
__global__ __launch_bounds__(256) void proj_kernel(const u16* __restrict__ projw,
                                                   const float* __restrict__ projb,
                                                   const u16* __restrict__ ht,
                                                   const float* __restrict__ x,
                                                   float* __restrict__ out) {
  const int nblk = blockIdx.x, mblk = blockIdx.y, b = blockIdx.z;
  const int tid = threadIdx.x;
  const int w = tid >> 6, l = tid & 63, quad = l >> 4, col = l & 15;
  const int m0 = mblk * 64 + w * 16;
  const int n0 = nblk * 64;
  __shared__ __align__(16) u16 als[64 * 256];   // 32 KiB
  __shared__ __align__(16) u16 bls[64 * 256];   // 32 KiB
  {
    const u16* asrc = projw + (size_t)(mblk * 64) * kC;
    const u16* bsrc = ht + (size_t)b * (kN * kC) + (size_t)n0 * kC;
#pragma unroll
    for (int p = 0; p < 8; ++p) {
      const int li = p * 256 + tid;
      const int row = li >> 5, ch = li & 31;
      const int sw = (ch ^ (row & 7)) * 8;
      *reinterpret_cast<bf16x8*>(&als[row * 256 + sw]) = ldb8(asrc + li * 8);
      *reinterpret_cast<bf16x8*>(&bls[row * 256 + sw]) = ldb8(bsrc + li * 8);
    }
  }
  __syncthreads();
  f32x4 acc[4] = {{0,0,0,0},{0,0,0,0},{0,0,0,0},{0,0,0,0}};
  const u16* arow = &als[(w * 16 + col) * 256];
  const int kx = col & 7;
#pragma unroll
  for (int ks = 0; ks < 8; ++ks) {
    const bf16x8 af = ldb8(arow + (((ks * 4 + quad) ^ kx)) * 8);
#pragma unroll
    for (int nt = 0; nt < 4; ++nt) {
      const bf16x8 bfr =
          ldb8(&bls[(nt * 16 + col) * 256 + (((ks * 4 + quad) ^ kx)) * 8]);
      acc[nt] = MFMA16x16x32(af, bfr, acc[nt]);
    }
  }
#pragma unroll
  for (int nt = 0; nt < 4; ++nt) {
    const int t = n0 + nt * 16 + col;
#pragma unroll
    for (int r = 0; r < 4; ++r) {
      const int o = m0 + quad * 4 + r;
      const int idx = b * (kC * kN) + o * kN + t;
      out[idx] = acc[nt][r] + projb[o] + x[idx];
    }
  }
}

extern "C" void kernel_launch(void* const* d_in, const int* in_sizes, int n_in,
                              void* d_out, int out_size, void* d_ws, size_t ws_size,
                              hipStream_t stream) {
  const float* x = (const float*)d_in[0];
  const float* gnw = (const float*)d_in[1];
  const float* gnb = (const float*)d_in[2];
  const float* qkvw_f = (const float*)d_in[3];
  const float* qkvb = (const float*)d_in[4];
  const float* projw_f = (const float*)d_in[5];
  const float* projb = (const float*)d_in[6];
  float* out = (float*)d_out;

  char* ws = (char*)d_ws;
  u16* xnT = (u16*)(ws);                      // 8 MiB
  u16* qt = (u16*)(ws + (8u << 20));          // 8 MiB
  u16* kt = (u16*)(ws + (16u << 20));         // 8 MiB
  u16* vv = (u16*)(ws + (24u << 20));         // 8 MiB
  u16* ht = (u16*)(ws + (32u << 20));         // 8 MiB
  u16* qkvw = (u16*)(ws + (40u << 20));       // 384 KiB
  u16* projw = (u16*)(ws + (41u << 20));      // 128 KiB

  gn_kernel<<<dim3(33, 4), dim3(1024), 0, stream>>>(x, gnw, gnb, xnT,
                                                    qkvw_f, qkvw, 768 * kC,
                                                    projw_f, projw);
  qkv_gemm<<<dim3(64, 3, 4), dim3(256), 0, stream>>>(qkvw, qkvb, xnT, qt, kt, vv);
  attn_split<<<dim3(512), dim3(512), 0, stream>>>(qt, kt, vv, ht);
  proj_kernel<<<dim3(64, 4, 4), dim3(256), 0, stream>>>(projw, projb, ht, x, out);
}

// Round 17
// 189.765 us; speedup vs baseline: 1.0448x; 1.0448x over previous
//
#include <hip/hip_runtime.h>

typedef unsigned short u16;
typedef unsigned int u32;
typedef __bf16 bf16x8 __attribute__((ext_vector_type(8)));
typedef float f32x4 __attribute__((ext_vector_type(4)));
typedef u16 u16x4 __attribute__((ext_vector_type(4)));
typedef u16 u16x8 __attribute__((ext_vector_type(8)));

#define MFMA16x16x32(a, b, c) __builtin_amdgcn_mfma_f32_16x16x32_bf16((a), (b), (c), 0, 0, 0)

static constexpr int kB = 4;
static constexpr int kC = 256;
static constexpr int kN = 4096;     // H*W
static constexpr int kHeads = 4;    // per batch
static constexpr int kD = 64;       // head dim
static constexpr float kScale = 0.35355339059327373f;   // 64^-0.25 (K side)
static constexpr float kScaleQ = 0.51006971545f;        // 64^-0.25 * log2(e) (Q side)

__device__ __forceinline__ u16 f2bf(float f) {
  union { float f; u32 i; } v; v.f = f;
  return (u16)((v.i + 0x7fffu + ((v.i >> 16) & 1u)) >> 16);
}
__device__ __forceinline__ bf16x8 ldb8(const u16* p) {
  return *reinterpret_cast<const bf16x8*>(p);
}
// r21 (validated): raw v_exp_f32 (2^x); OCML exp2f carries fixup VALU.
__device__ __forceinline__ float fast_exp2(float x) {
#if __has_builtin(__builtin_amdgcn_exp2f)
  return __builtin_amdgcn_exp2f(x);
#else
  float r;
  asm("v_exp_f32 %0, %1" : "=v"(r) : "v"(x));
  return r;
#endif
}

// ---------------------------------------------------------------------------
// r30: standalone weight conversion restored (r29's gn-fold coincided with a
// ~10us total regression; unbundling to isolate).
// ---------------------------------------------------------------------------
__global__ void convert_bf16_2(const float* __restrict__ in1, u16* __restrict__ out1,
                               int n1, const float* __restrict__ in2,
                               u16* __restrict__ out2, int n2) {
  const int total = n1 + n2;
  for (int i = blockIdx.x * blockDim.x + threadIdx.x; i < total;
       i += gridDim.x * blockDim.x) {
    if (i < n1) out1[i] = f2bf(in1[i]);
    else out2[i - n1] = f2bf(in2[i - n1]);
  }
}

// ---------------------------------------------------------------------------
// GroupNorm (validated r4). Writes bf16 transposed xnT[b][t][c].
// ---------------------------------------------------------------------------
__global__ __launch_bounds__(1024) void gn_kernel(const float* __restrict__ x,
                                                  const float* __restrict__ gnw,
                                                  const float* __restrict__ gnb,
                                                  u16* __restrict__ xnT) {
  const int g = blockIdx.x, b = blockIdx.y;
  const int tid = threadIdx.x;
  const float* xb = x + b * (kC * kN) + g * 8 * kN;
  float vals[4][8];
  float s = 0.f, ss = 0.f;
#pragma unroll
  for (int kk = 0; kk < 4; ++kk) {
    const int t = tid + kk * 1024;
#pragma unroll
    for (int c = 0; c < 8; ++c) {
      const float v_ = xb[c * kN + t];
      vals[kk][c] = v_;
      s += v_; ss += v_ * v_;
    }
  }
#pragma unroll
  for (int off = 32; off > 0; off >>= 1) {
    s += __shfl_down(s, off);
    ss += __shfl_down(ss, off);
  }
  __shared__ float rbuf[32];
  const int wid = tid >> 6, lane = tid & 63;
  if (lane == 0) { rbuf[wid] = s; rbuf[16 + wid] = ss; }
  __syncthreads();
  if (tid < 64) {
    float s2 = (lane < 16) ? rbuf[lane] : 0.f;
    float ss2 = (lane < 16) ? rbuf[16 + lane] : 0.f;
#pragma unroll
    for (int off = 8; off > 0; off >>= 1) {
      s2 += __shfl_down(s2, off);
      ss2 += __shfl_down(ss2, off);
    }
    if (lane == 0) { rbuf[0] = s2; rbuf[1] = ss2; }
  }
  __syncthreads();
  const float inv_n = 1.f / 32768.f;
  const float mu = rbuf[0] * inv_n;
  const float var = rbuf[1] * inv_n - mu * mu;
  const float rs = rsqrtf(var + 1e-5f);
  float wv[8], bv[8];
#pragma unroll
  for (int c = 0; c < 8; ++c) {
    const float wgt = gnw[g * 8 + c] * rs;
    wv[c] = wgt;
    bv[c] = gnb[g * 8 + c] - mu * wgt;
  }
  u16* ob = xnT + b * (kN * kC) + g * 8;
#pragma unroll
  for (int kk = 0; kk < 4; ++kk) {
    const int t = tid + kk * 1024;
    u16x8 pk;
#pragma unroll
    for (int c = 0; c < 8; ++c) pk[c] = f2bf(vals[kk][c] * wv[c] + bv[c]);
    *reinterpret_cast<u16x8*>(ob + t * kC) = pk;
  }
}

// ---------------------------------------------------------------------------
// QKV GEMM. r22 (validated): LDS staging + XOR swizzle. r28: M-loop (B panel
// staged once per block; neutral on time, less HBM).
// Epilogue: r19 V slot-permutation m = 8*(col>>2)+4*(nt&1)+(col&3) within
// each 32-col block matches attn's in-register P order; Q side folds log2e.
// ---------------------------------------------------------------------------
__global__ __launch_bounds__(256) void qkv_gemm(const u16* __restrict__ qkvw,
                                                const float* __restrict__ qkvb,
                                                const u16* __restrict__ xnT,
                                                u16* __restrict__ qt,
                                                u16* __restrict__ kt,
                                                u16* __restrict__ vv) {
  const int nblk = blockIdx.x, mseg = blockIdx.y, b = blockIdx.z;
  const int tid = threadIdx.x;
  const int w = tid >> 6, l = tid & 63, quad = l >> 4, col = l & 15;
  const int n0 = nblk * 64;
  __shared__ __align__(16) u16 als[64 * 256];   // 32 KiB (A tile, reused)
  __shared__ __align__(16) u16 bls[64 * 256];   // 32 KiB (B panel, once)
  {
    const u16* bsrc = xnT + (size_t)b * (kN * kC) + (size_t)n0 * kC;
#pragma unroll
    for (int p = 0; p < 8; ++p) {
      const int li = p * 256 + tid;        // [0,2048)
      const int row = li >> 5, ch = li & 31;
      const int sw = (ch ^ (row & 7)) * 8;
      *reinterpret_cast<bf16x8*>(&bls[row * 256 + sw]) = ldb8(bsrc + li * 8);
    }
  }
  const int kx = col & 7;
  for (int msub = 0; msub < 4; ++msub) {
    const int mblk = mseg * 4 + msub;
    const int m0 = mblk * 64 + w * 16;
    {
      const u16* asrc = qkvw + (size_t)(mblk * 64) * kC;
#pragma unroll
      for (int p = 0; p < 8; ++p) {
        const int li = p * 256 + tid;
        const int row = li >> 5, ch = li & 31;
        const int sw = (ch ^ (row & 7)) * 8;
        *reinterpret_cast<bf16x8*>(&als[row * 256 + sw]) = ldb8(asrc + li * 8);
      }
    }
    __syncthreads();
    f32x4 acc[4] = {{0,0,0,0},{0,0,0,0},{0,0,0,0},{0,0,0,0}};
    const u16* arow = &als[(w * 16 + col) * 256];
#pragma unroll
    for (int ks = 0; ks < 8; ++ks) {
      const bf16x8 af = ldb8(arow + (((ks * 4 + quad) ^ kx)) * 8);
#pragma unroll
      for (int nt = 0; nt < 4; ++nt) {
        const bf16x8 bfr =
            ldb8(&bls[(nt * 16 + col) * 256 + (((ks * 4 + quad) ^ kx)) * 8]);
        acc[nt] = MFMA16x16x32(af, bfr, acc[nt]);
      }
    }
    const int o_base = m0 + quad * 4;
    const int head = o_base / 192;
    const int rr = o_base % 192;
    const int bh = b * kHeads + head;
    const int seg = rr >> 6;
    const int c0 = rr & 63;
    float bias[4];
#pragma unroll
    for (int r = 0; r < 4; ++r) bias[r] = qkvb[o_base + r];
    const float sc = (seg == 0) ? kScaleQ : kScale;
#pragma unroll
    for (int nt = 0; nt < 4; ++nt) {
      const int t = n0 + nt * 16 + col;
      if (seg == 2) {
        const int tp = n0 + (nt >> 1) * 32 + 8 * (col >> 2) + 4 * (nt & 1) + (col & 3);
#pragma unroll
        for (int r = 0; r < 4; ++r)
          vv[bh * (kD * kN) + (c0 + r) * kN + tp] = f2bf(acc[nt][r] + bias[r]);
      } else {
        u16* dst = (seg == 0 ? qt : kt) + bh * (kN * kD) + t * kD + c0;
        u16x4 pk;
#pragma unroll
        for (int r = 0; r < 4; ++r) pk[r] = f2bf((acc[nt][r] + bias[r]) * sc);
        *reinterpret_cast<u16x4*>(dst) = pk;
      }
    }
    __syncthreads();   // protect als before next m-tile overwrites it
  }
}

// ---------------------------------------------------------------------------
// Flash attention, UNSPLIT. Validated ladder: r20 staging, r21 fast_exp2,
// r24 fused combine, r27 4-phase, r28 setprio (+4.5%), r29 XCD remap
// (FETCH 69.7->12.3MB, dur 77->75.7; attn memory-side is DONE — remaining
// cost is the MFMA+VALU serial chain, MfmaUtil 44 + VALUBusy 40).
// ---------------------------------------------------------------------------
__global__ __launch_bounds__(512, 4) void attn_split(const u16* __restrict__ qt,
                                                     const u16* __restrict__ kt,
                                                     const u16* __restrict__ vv,
                                                     u16* __restrict__ ht) {
  const int bid = blockIdx.x;
  const int xcd = bid & 7, j = bid >> 3;
  const int bh = (xcd << 1) | (j >> 5);
  const int tblk = j & 31;
  const int tid = threadIdx.x;
  const int w = tid >> 6, l = tid & 63, quad = l >> 4, col = l & 15;
  const int t0 = tblk * 128 + w * 16;          // 8 waves x 16 q-rows
  const u16* qb = qt + bh * (kN * kD);
  const u16* kb = kt + bh * (kN * kD);
  const u16* vb = vv + bh * (kD * kN);
  bf16x8 qf0, qf1;
  qf0 = ldb8(qb + (t0 + col) * kD + quad * 8);
  qf1 = ldb8(qb + (t0 + col) * kD + 32 + quad * 8);
  u16x8 ones_u;
#pragma unroll
  for (int i = 0; i < 8; ++i) ones_u[i] = 0x3f80;  // bf16 1.0
  const bf16x8 onesf = *reinterpret_cast<bf16x8*>(&ones_u);
  f32x4 oacc[4];
  f32x4 lacc = {0, 0, 0, 0};
#pragma unroll
  for (int ct = 0; ct < 4; ++ct) oacc[ct] = f32x4{0, 0, 0, 0};

  __shared__ __align__(16) u16 kls[2][4][32][64];   // 32 KiB: [buf][half]
  __shared__ __align__(16) u16 vls[2][4][32][64];   // 32 KiB
  constexpr int NIT = kN / 128;                      // 32
  constexpr int BUFSTRIDE = 4 * 32 * 64;             // 8192 u16

  // --- staging roles: 512 threads, 2 K-chunks + 2 V-chunks of 16B each ---
  const int r6 = tid >> 3, c3 = tid & 7;             // K chunk 0: row r6
  const u16* ksrc = kb + (size_t)r6 * kD + c3 * 8;   // chunk 1: +64 rows
  u16* kdst = &kls[0][r6 >> 5][r6 & 31][(c3 ^ (r6 & 7)) * 8];
  // V chunk 0: id=tid (half vh, row vr, chunk vc3); chunk 1: id+512 (half+2)
  const int vh = tid >> 8, vcc = tid & 255, vr = vcc >> 3, vc3 = vcc & 7;
  const int sa = vc3 >> 2, sq = vc3 & 3;
  const u16* vsrc = vb + (size_t)(2 * vr + sa) * kN + vh * 32 + sq * 8;
  u16* vdst = &vls[0][vh][vr][(((sa << 2) | sq) ^ (vr & 7)) * 8];

  // prologue: load tile 0 (4 chunks)
  bf16x8 kstg0 = ldb8(ksrc);
  bf16x8 kstg1 = ldb8(ksrc + (size_t)64 * kD);
  bf16x8 vstg0 = ldb8(vsrc);
  bf16x8 vstg1 = ldb8(vsrc + 64);

#pragma unroll 2
  for (int it = 0; it < NIT; ++it) {
    const int cb = (it & 1) * BUFSTRIDE;
    *reinterpret_cast<bf16x8*>(kdst + cb) = kstg0;
    *reinterpret_cast<bf16x8*>(kdst + cb + 2 * 2048) = kstg1;
    *reinterpret_cast<bf16x8*>(vdst + cb) = vstg0;
    *reinterpret_cast<bf16x8*>(vdst + cb + 2 * 2048) = vstg1;
    __syncthreads();
    if (it + 1 < NIT) {
      const size_t sb = (size_t)(it + 1) * 128;
      kstg0 = ldb8(ksrc + sb * kD);
      kstg1 = ldb8(ksrc + (sb + 64) * kD);
      vstg0 = ldb8(vsrc + sb);
      vstg1 = ldb8(vsrc + sb + 64);
    }
    const int kx = (col & 7) * 8;
    const int vslot = (((col & 1) << 2) | quad) ^ (col >> 1);
#pragma unroll
    for (int h = 0; h < 4; ++h) {
      const u16* kl = &kls[0][0][0][0] + cb + h * 2048;
      const u16* vl = &vls[0][0][0][0] + cb + h * 2048;
      const bf16x8 k00 = ldb8(kl + col * 64 + ((quad * 8) ^ kx));
      const bf16x8 k01 = ldb8(kl + col * 64 + ((32 + quad * 8) ^ kx));
      const bf16x8 k10 = ldb8(kl + (col + 16) * 64 + ((quad * 8) ^ kx));
      const bf16x8 k11 = ldb8(kl + (col + 16) * 64 + ((32 + quad * 8) ^ kx));
      bf16x8 vf[4];
#pragma unroll
      for (int ct = 0; ct < 4; ++ct)
        vf[ct] = ldb8(vl + (ct * 8 + (col >> 1)) * 64 + vslot * 8);
      f32x4 sa0 = {0, 0, 0, 0}, sa1 = {0, 0, 0, 0};
      __builtin_amdgcn_s_setprio(1);
      sa0 = MFMA16x16x32(k00, qf0, sa0);
      sa0 = MFMA16x16x32(k01, qf1, sa0);
      sa1 = MFMA16x16x32(k10, qf0, sa1);
      sa1 = MFMA16x16x32(k11, qf1, sa1);
      __builtin_amdgcn_s_setprio(0);
      const u32 e00 = __float_as_uint(fast_exp2(sa0[0]));
      const u32 e01 = __float_as_uint(fast_exp2(sa0[1]));
      const u32 e02 = __float_as_uint(fast_exp2(sa0[2]));
      const u32 e03 = __float_as_uint(fast_exp2(sa0[3]));
      const u32 e10 = __float_as_uint(fast_exp2(sa1[0]));
      const u32 e11 = __float_as_uint(fast_exp2(sa1[1]));
      const u32 e12 = __float_as_uint(fast_exp2(sa1[2]));
      const u32 e13 = __float_as_uint(fast_exp2(sa1[3]));
      union { u32 wd[4]; bf16x8 v; } pa;
      pa.wd[0] = __builtin_amdgcn_perm(e01, e00, 0x07060302u);
      pa.wd[1] = __builtin_amdgcn_perm(e03, e02, 0x07060302u);
      pa.wd[2] = __builtin_amdgcn_perm(e11, e10, 0x07060302u);
      pa.wd[3] = __builtin_amdgcn_perm(e13, e12, 0x07060302u);
      __builtin_amdgcn_s_setprio(1);
#pragma unroll
      for (int ct = 0; ct < 4; ++ct)
        oacc[ct] = MFMA16x16x32(pa.v, vf[ct], oacc[ct]);
      lacc = MFMA16x16x32(pa.v, onesf, lacc);
      __builtin_amdgcn_s_setprio(0);
    }
  }
  // epilogue: divide by l (every col holds l[q]) and write ht bf16 directly
  const int b = bh >> 2, head = bh & 3;
  u16* hb = ht + (size_t)b * (kN * kC) + head * kD;
#pragma unroll
  for (int r = 0; r < 4; ++r) {
    const int t = t0 + quad * 4 + r;
    const float inv = 1.f / lacc[r];
#pragma unroll
    for (int ct = 0; ct < 4; ++ct)
      hb[(size_t)t * kC + ct * 16 + col] = f2bf(oacc[ct][r] * inv);
  }
}

// ---------------------------------------------------------------------------
// Proj GEMM + bias + residual: out fp32 (B,C,H,W). r22 (validated): LDS
// staging (A=projw 64x256 tile, B=ht 64x256 tile, coalesced + swizzled).
// ---------------------------------------------------------------------------
__global__ __launch_bounds__(256) void proj_kernel(const u16* __restrict__ projw,
                                                   const float* __restrict__ projb,
                                                   const u16* __restrict__ ht,
                                                   const float* __restrict__ x,
                                                   float* __restrict__ out) {
  const int nblk = blockIdx.x, mblk = blockIdx.y, b = blockIdx.z;
  const int tid = threadIdx.x;
  const int w = tid >> 6, l = tid & 63, quad = l >> 4, col = l & 15;
  const int m0 = mblk * 64 + w * 16;
  const int n0 = nblk * 64;
  __shared__ __align__(16) u16 als[64 * 256];   // 32 KiB
  __shared__ __align__(16) u16 bls[64 * 256];   // 32 KiB
  {
    const u16* asrc = projw + (size_t)(mblk * 64) * kC;
    const u16* bsrc = ht + (size_t)b * (kN * kC) + (size_t)n0 * kC;
#pragma unroll
    for (int p = 0; p < 8; ++p) {
      const int li = p * 256 + tid;
      const int row = li >> 5, ch = li & 31;
      const int sw = (ch ^ (row & 7)) * 8;
      *reinterpret_cast<bf16x8*>(&als[row * 256 + sw]) = ldb8(asrc + li * 8);
      *reinterpret_cast<bf16x8*>(&bls[row * 256 + sw]) = ldb8(bsrc + li * 8);
    }
  }
  __syncthreads();
  f32x4 acc[4] = {{0,0,0,0},{0,0,0,0},{0,0,0,0},{0,0,0,0}};
  const u16* arow = &als[(w * 16 + col) * 256];
  const int kx = col & 7;
#pragma unroll
  for (int ks = 0; ks < 8; ++ks) {
    const bf16x8 af = ldb8(arow + (((ks * 4 + quad) ^ kx)) * 8);
#pragma unroll
    for (int nt = 0; nt < 4; ++nt) {
      const bf16x8 bfr =
          ldb8(&bls[(nt * 16 + col) * 256 + (((ks * 4 + quad) ^ kx)) * 8]);
      acc[nt] = MFMA16x16x32(af, bfr, acc[nt]);
    }
  }
#pragma unroll
  for (int nt = 0; nt < 4; ++nt) {
    const int t = n0 + nt * 16 + col;
#pragma unroll
    for (int r = 0; r < 4; ++r) {
      const int o = m0 + quad * 4 + r;
      const int idx = b * (kC * kN) + o * kN + t;
      out[idx] = acc[nt][r] + projb[o] + x[idx];
    }
  }
}

extern "C" void kernel_launch(void* const* d_in, const int* in_sizes, int n_in,
                              void* d_out, int out_size, void* d_ws, size_t ws_size,
                              hipStream_t stream) {
  const float* x = (const float*)d_in[0];
  const float* gnw = (const float*)d_in[1];
  const float* gnb = (const float*)d_in[2];
  const float* qkvw_f = (const float*)d_in[3];
  const float* qkvb = (const float*)d_in[4];
  const float* projw_f = (const float*)d_in[5];
  const float* projb = (const float*)d_in[6];
  float* out = (float*)d_out;

  char* ws = (char*)d_ws;
  u16* xnT = (u16*)(ws);                      // 8 MiB
  u16* qt = (u16*)(ws + (8u << 20));          // 8 MiB
  u16* kt = (u16*)(ws + (16u << 20));         // 8 MiB
  u16* vv = (u16*)(ws + (24u << 20));         // 8 MiB
  u16* ht = (u16*)(ws + (32u << 20));         // 8 MiB
  u16* qkvw = (u16*)(ws + (40u << 20));       // 384 KiB
  u16* projw = (u16*)(ws + (41u << 20));      // 128 KiB

  convert_bf16_2<<<dim3(256), dim3(256), 0, stream>>>(qkvw_f, qkvw, 768 * kC,
                                                      projw_f, projw, kC * kC);
  gn_kernel<<<dim3(32, 4), dim3(1024), 0, stream>>>(x, gnw, gnb, xnT);
  qkv_gemm<<<dim3(64, 3, 4), dim3(256), 0, stream>>>(qkvw, qkvb, xnT, qt, kt, vv);
  attn_split<<<dim3(512), dim3(512), 0, stream>>>(qt, kt, vv, ht);
  proj_kernel<<<dim3(64, 4, 4), dim3(256), 0, stream>>>(projw, projb, ht, x, out);
}

// Round 18
// 185.600 us; speedup vs baseline: 1.0682x; 1.0224x over previous
//
#include <hip/hip_runtime.h>

typedef unsigned short u16;
typedef unsigned int u32;
typedef __bf16 bf16x8 __attribute__((ext_vector_type(8)));
typedef float f32x4 __attribute__((ext_vector_type(4)));
typedef u16 u16x4 __attribute__((ext_vector_type(4)));
typedef u16 u16x8 __attribute__((ext_vector_type(8)));

#define MFMA16x16x32(a, b, c) __builtin_amdgcn_mfma_f32_16x16x32_bf16((a), (b), (c), 0, 0, 0)

static constexpr int kB = 4;
static constexpr int kC = 256;
static constexpr int kN = 4096;     // H*W
static constexpr int kHeads = 4;    // per batch
static constexpr int kD = 64;       // head dim
static constexpr float kScale = 0.35355339059327373f;   // 64^-0.25 (K side)
static constexpr float kScaleQ = 0.51006971545f;        // 64^-0.25 * log2(e) (Q side)

__device__ __forceinline__ u16 f2bf(float f) {
  union { float f; u32 i; } v; v.f = f;
  return (u16)((v.i + 0x7fffu + ((v.i >> 16) & 1u)) >> 16);
}
__device__ __forceinline__ bf16x8 ldb8(const u16* p) {
  return *reinterpret_cast<const bf16x8*>(p);
}
// r21 (validated): raw v_exp_f32 (2^x); OCML exp2f carries fixup VALU.
__device__ __forceinline__ float fast_exp2(float x) {
#if __has_builtin(__builtin_amdgcn_exp2f)
  return __builtin_amdgcn_exp2f(x);
#else
  float r;
  asm("v_exp_f32 %0, %1" : "=v"(r) : "v"(x));
  return r;
#endif
}

// ---------------------------------------------------------------------------
// Standalone weight conversion (validated r24/r30 form).
// ---------------------------------------------------------------------------
__global__ void convert_bf16_2(const float* __restrict__ in1, u16* __restrict__ out1,
                               int n1, const float* __restrict__ in2,
                               u16* __restrict__ out2, int n2) {
  const int total = n1 + n2;
  for (int i = blockIdx.x * blockDim.x + threadIdx.x; i < total;
       i += gridDim.x * blockDim.x) {
    if (i < n1) out1[i] = f2bf(in1[i]);
    else out2[i - n1] = f2bf(in2[i - n1]);
  }
}

// ---------------------------------------------------------------------------
// GroupNorm (validated r4). Writes bf16 transposed xnT[b][t][c].
// ---------------------------------------------------------------------------
__global__ __launch_bounds__(1024) void gn_kernel(const float* __restrict__ x,
                                                  const float* __restrict__ gnw,
                                                  const float* __restrict__ gnb,
                                                  u16* __restrict__ xnT) {
  const int g = blockIdx.x, b = blockIdx.y;
  const int tid = threadIdx.x;
  const float* xb = x + b * (kC * kN) + g * 8 * kN;
  float vals[4][8];
  float s = 0.f, ss = 0.f;
#pragma unroll
  for (int kk = 0; kk < 4; ++kk) {
    const int t = tid + kk * 1024;
#pragma unroll
    for (int c = 0; c < 8; ++c) {
      const float v_ = xb[c * kN + t];
      vals[kk][c] = v_;
      s += v_; ss += v_ * v_;
    }
  }
#pragma unroll
  for (int off = 32; off > 0; off >>= 1) {
    s += __shfl_down(s, off);
    ss += __shfl_down(ss, off);
  }
  __shared__ float rbuf[32];
  const int wid = tid >> 6, lane = tid & 63;
  if (lane == 0) { rbuf[wid] = s; rbuf[16 + wid] = ss; }
  __syncthreads();
  if (tid < 64) {
    float s2 = (lane < 16) ? rbuf[lane] : 0.f;
    float ss2 = (lane < 16) ? rbuf[16 + lane] : 0.f;
#pragma unroll
    for (int off = 8; off > 0; off >>= 1) {
      s2 += __shfl_down(s2, off);
      ss2 += __shfl_down(ss2, off);
    }
    if (lane == 0) { rbuf[0] = s2; rbuf[1] = ss2; }
  }
  __syncthreads();
  const float inv_n = 1.f / 32768.f;
  const float mu = rbuf[0] * inv_n;
  const float var = rbuf[1] * inv_n - mu * mu;
  const float rs = rsqrtf(var + 1e-5f);
  float wv[8], bv[8];
#pragma unroll
  for (int c = 0; c < 8; ++c) {
    const float wgt = gnw[g * 8 + c] * rs;
    wv[c] = wgt;
    bv[c] = gnb[g * 8 + c] - mu * wgt;
  }
  u16* ob = xnT + b * (kN * kC) + g * 8;
#pragma unroll
  for (int kk = 0; kk < 4; ++kk) {
    const int t = tid + kk * 1024;
    u16x8 pk;
#pragma unroll
    for (int c = 0; c < 8; ++c) pk[c] = f2bf(vals[kk][c] * wv[c] + bv[c]);
    *reinterpret_cast<u16x8*>(ob + t * kC) = pk;
  }
}

// ---------------------------------------------------------------------------
// QKV GEMM. r22: LDS staging + XOR swizzle. r28: M-loop (B staged once).
// r31: T14 register-prefetch across the m-loop — A(m+1) global loads issue
// right after the barrier and land in regs while compute+epilogue of m runs;
// ds_write at the top of iteration m+1. Ping-pong ar[2][8] (compile-time
// indexed after full unroll; no wrap arithmetic — avoids r17's VALU bloat).
// Epilogue: r19 V slot-permutation m = 8*(col>>2)+4*(nt&1)+(col&3); Q side
// folds log2e.
// ---------------------------------------------------------------------------
__global__ __launch_bounds__(256) void qkv_gemm(const u16* __restrict__ qkvw,
                                                const float* __restrict__ qkvb,
                                                const u16* __restrict__ xnT,
                                                u16* __restrict__ qt,
                                                u16* __restrict__ kt,
                                                u16* __restrict__ vv) {
  const int nblk = blockIdx.x, mseg = blockIdx.y, b = blockIdx.z;
  const int tid = threadIdx.x;
  const int w = tid >> 6, l = tid & 63, quad = l >> 4, col = l & 15;
  const int n0 = nblk * 64;
  __shared__ __align__(16) u16 als[64 * 256];   // 32 KiB (A tile, reused)
  __shared__ __align__(16) u16 bls[64 * 256];   // 32 KiB (B panel, once)
  // prefetch A(0) into regs (latency overlaps B staging below)
  bf16x8 ar[2][8];
  {
    const u16* asrc = qkvw + (size_t)(mseg * 4 * 64) * kC;
#pragma unroll
    for (int p = 0; p < 8; ++p)
      ar[0][p] = ldb8(asrc + (size_t)(p * 256 + tid) * 8);
  }
  {
    const u16* bsrc = xnT + (size_t)b * (kN * kC) + (size_t)n0 * kC;
#pragma unroll
    for (int p = 0; p < 8; ++p) {
      const int li = p * 256 + tid;        // [0,2048)
      const int row = li >> 5, ch = li & 31;
      const int sw = (ch ^ (row & 7)) * 8;
      *reinterpret_cast<bf16x8*>(&bls[row * 256 + sw]) = ldb8(bsrc + li * 8);
    }
  }
  const int kx = col & 7;
#pragma unroll
  for (int msub = 0; msub < 4; ++msub) {
    const int cur = msub & 1, nxt = cur ^ 1;
    const int mblk = mseg * 4 + msub;
    const int m0 = mblk * 64 + w * 16;
    // ds_write A(msub) from regs
#pragma unroll
    for (int p = 0; p < 8; ++p) {
      const int li = p * 256 + tid;
      const int row = li >> 5, ch = li & 31;
      const int sw = (ch ^ (row & 7)) * 8;
      *reinterpret_cast<bf16x8*>(&als[row * 256 + sw]) = ar[cur][p];
    }
    __syncthreads();
    // issue A(msub+1) loads; latency hidden under compute+epilogue
    if (msub < 3) {
      const u16* asrc = qkvw + (size_t)((mblk + 1) * 64) * kC;
#pragma unroll
      for (int p = 0; p < 8; ++p)
        ar[nxt][p] = ldb8(asrc + (size_t)(p * 256 + tid) * 8);
    }
    f32x4 acc[4] = {{0,0,0,0},{0,0,0,0},{0,0,0,0},{0,0,0,0}};
    const u16* arow = &als[(w * 16 + col) * 256];
#pragma unroll
    for (int ks = 0; ks < 8; ++ks) {
      const bf16x8 af = ldb8(arow + (((ks * 4 + quad) ^ kx)) * 8);
#pragma unroll
      for (int nt = 0; nt < 4; ++nt) {
        const bf16x8 bfr =
            ldb8(&bls[(nt * 16 + col) * 256 + (((ks * 4 + quad) ^ kx)) * 8]);
        acc[nt] = MFMA16x16x32(af, bfr, acc[nt]);
      }
    }
    const int o_base = m0 + quad * 4;
    const int head = o_base / 192;
    const int rr = o_base % 192;
    const int bh = b * kHeads + head;
    const int seg = rr >> 6;
    const int c0 = rr & 63;
    float bias[4];
#pragma unroll
    for (int r = 0; r < 4; ++r) bias[r] = qkvb[o_base + r];
    const float sc = (seg == 0) ? kScaleQ : kScale;
#pragma unroll
    for (int nt = 0; nt < 4; ++nt) {
      const int t = n0 + nt * 16 + col;
      if (seg == 2) {
        const int tp = n0 + (nt >> 1) * 32 + 8 * (col >> 2) + 4 * (nt & 1) + (col & 3);
#pragma unroll
        for (int r = 0; r < 4; ++r)
          vv[bh * (kD * kN) + (c0 + r) * kN + tp] = f2bf(acc[nt][r] + bias[r]);
      } else {
        u16* dst = (seg == 0 ? qt : kt) + bh * (kN * kD) + t * kD + c0;
        u16x4 pk;
#pragma unroll
        for (int r = 0; r < 4; ++r) pk[r] = f2bf((acc[nt][r] + bias[r]) * sc);
        *reinterpret_cast<u16x4*>(dst) = pk;
      }
    }
    __syncthreads();   // protect als before next m-tile overwrites it
  }
}

// ---------------------------------------------------------------------------
// Flash attention, UNSPLIT. Validated ladder: r20 staging, r21 fast_exp2,
// r24 fused combine, r27 4-phase, r28 setprio (+4.5%), r29 XCD remap
// (FETCH 69.7->12.3MB). attn is at its MFMA+VALU serial-chain floor
// (MfmaUtil 44 + VALUBusy 40); untouched this round.
// ---------------------------------------------------------------------------
__global__ __launch_bounds__(512, 4) void attn_split(const u16* __restrict__ qt,
                                                     const u16* __restrict__ kt,
                                                     const u16* __restrict__ vv,
                                                     u16* __restrict__ ht) {
  const int bid = blockIdx.x;
  const int xcd = bid & 7, j = bid >> 3;
  const int bh = (xcd << 1) | (j >> 5);
  const int tblk = j & 31;
  const int tid = threadIdx.x;
  const int w = tid >> 6, l = tid & 63, quad = l >> 4, col = l & 15;
  const int t0 = tblk * 128 + w * 16;          // 8 waves x 16 q-rows
  const u16* qb = qt + bh * (kN * kD);
  const u16* kb = kt + bh * (kN * kD);
  const u16* vb = vv + bh * (kD * kN);
  bf16x8 qf0, qf1;
  qf0 = ldb8(qb + (t0 + col) * kD + quad * 8);
  qf1 = ldb8(qb + (t0 + col) * kD + 32 + quad * 8);
  u16x8 ones_u;
#pragma unroll
  for (int i = 0; i < 8; ++i) ones_u[i] = 0x3f80;  // bf16 1.0
  const bf16x8 onesf = *reinterpret_cast<bf16x8*>(&ones_u);
  f32x4 oacc[4];
  f32x4 lacc = {0, 0, 0, 0};
#pragma unroll
  for (int ct = 0; ct < 4; ++ct) oacc[ct] = f32x4{0, 0, 0, 0};

  __shared__ __align__(16) u16 kls[2][4][32][64];   // 32 KiB: [buf][half]
  __shared__ __align__(16) u16 vls[2][4][32][64];   // 32 KiB
  constexpr int NIT = kN / 128;                      // 32
  constexpr int BUFSTRIDE = 4 * 32 * 64;             // 8192 u16

  // --- staging roles: 512 threads, 2 K-chunks + 2 V-chunks of 16B each ---
  const int r6 = tid >> 3, c3 = tid & 7;             // K chunk 0: row r6
  const u16* ksrc = kb + (size_t)r6 * kD + c3 * 8;   // chunk 1: +64 rows
  u16* kdst = &kls[0][r6 >> 5][r6 & 31][(c3 ^ (r6 & 7)) * 8];
  // V chunk 0: id=tid (half vh, row vr, chunk vc3); chunk 1: id+512 (half+2)
  const int vh = tid >> 8, vcc = tid & 255, vr = vcc >> 3, vc3 = vcc & 7;
  const int sa = vc3 >> 2, sq = vc3 & 3;
  const u16* vsrc = vb + (size_t)(2 * vr + sa) * kN + vh * 32 + sq * 8;
  u16* vdst = &vls[0][vh][vr][(((sa << 2) | sq) ^ (vr & 7)) * 8];

  // prologue: load tile 0 (4 chunks)
  bf16x8 kstg0 = ldb8(ksrc);
  bf16x8 kstg1 = ldb8(ksrc + (size_t)64 * kD);
  bf16x8 vstg0 = ldb8(vsrc);
  bf16x8 vstg1 = ldb8(vsrc + 64);

#pragma unroll 2
  for (int it = 0; it < NIT; ++it) {
    const int cb = (it & 1) * BUFSTRIDE;
    *reinterpret_cast<bf16x8*>(kdst + cb) = kstg0;
    *reinterpret_cast<bf16x8*>(kdst + cb + 2 * 2048) = kstg1;
    *reinterpret_cast<bf16x8*>(vdst + cb) = vstg0;
    *reinterpret_cast<bf16x8*>(vdst + cb + 2 * 2048) = vstg1;
    __syncthreads();
    if (it + 1 < NIT) {
      const size_t sb = (size_t)(it + 1) * 128;
      kstg0 = ldb8(ksrc + sb * kD);
      kstg1 = ldb8(ksrc + (sb + 64) * kD);
      vstg0 = ldb8(vsrc + sb);
      vstg1 = ldb8(vsrc + sb + 64);
    }
    const int kx = (col & 7) * 8;
    const int vslot = (((col & 1) << 2) | quad) ^ (col >> 1);
#pragma unroll
    for (int h = 0; h < 4; ++h) {
      const u16* kl = &kls[0][0][0][0] + cb + h * 2048;
      const u16* vl = &vls[0][0][0][0] + cb + h * 2048;
      const bf16x8 k00 = ldb8(kl + col * 64 + ((quad * 8) ^ kx));
      const bf16x8 k01 = ldb8(kl + col * 64 + ((32 + quad * 8) ^ kx));
      const bf16x8 k10 = ldb8(kl + (col + 16) * 64 + ((quad * 8) ^ kx));
      const bf16x8 k11 = ldb8(kl + (col + 16) * 64 + ((32 + quad * 8) ^ kx));
      bf16x8 vf[4];
#pragma unroll
      for (int ct = 0; ct < 4; ++ct)
        vf[ct] = ldb8(vl + (ct * 8 + (col >> 1)) * 64 + vslot * 8);
      f32x4 sa0 = {0, 0, 0, 0}, sa1 = {0, 0, 0, 0};
      __builtin_amdgcn_s_setprio(1);
      sa0 = MFMA16x16x32(k00, qf0, sa0);
      sa0 = MFMA16x16x32(k01, qf1, sa0);
      sa1 = MFMA16x16x32(k10, qf0, sa1);
      sa1 = MFMA16x16x32(k11, qf1, sa1);
      __builtin_amdgcn_s_setprio(0);
      const u32 e00 = __float_as_uint(fast_exp2(sa0[0]));
      const u32 e01 = __float_as_uint(fast_exp2(sa0[1]));
      const u32 e02 = __float_as_uint(fast_exp2(sa0[2]));
      const u32 e03 = __float_as_uint(fast_exp2(sa0[3]));
      const u32 e10 = __float_as_uint(fast_exp2(sa1[0]));
      const u32 e11 = __float_as_uint(fast_exp2(sa1[1]));
      const u32 e12 = __float_as_uint(fast_exp2(sa1[2]));
      const u32 e13 = __float_as_uint(fast_exp2(sa1[3]));
      union { u32 wd[4]; bf16x8 v; } pa;
      pa.wd[0] = __builtin_amdgcn_perm(e01, e00, 0x07060302u);
      pa.wd[1] = __builtin_amdgcn_perm(e03, e02, 0x07060302u);
      pa.wd[2] = __builtin_amdgcn_perm(e11, e10, 0x07060302u);
      pa.wd[3] = __builtin_amdgcn_perm(e13, e12, 0x07060302u);
      __builtin_amdgcn_s_setprio(1);
#pragma unroll
      for (int ct = 0; ct < 4; ++ct)
        oacc[ct] = MFMA16x16x32(pa.v, vf[ct], oacc[ct]);
      lacc = MFMA16x16x32(pa.v, onesf, lacc);
      __builtin_amdgcn_s_setprio(0);
    }
  }
  // epilogue: divide by l (every col holds l[q]) and write ht bf16 directly
  const int b = bh >> 2, head = bh & 3;
  u16* hb = ht + (size_t)b * (kN * kC) + head * kD;
#pragma unroll
  for (int r = 0; r < 4; ++r) {
    const int t = t0 + quad * 4 + r;
    const float inv = 1.f / lacc[r];
#pragma unroll
    for (int ct = 0; ct < 4; ++ct)
      hb[(size_t)t * kC + ct * 16 + col] = f2bf(oacc[ct][r] * inv);
  }
}

// ---------------------------------------------------------------------------
// Proj GEMM + bias + residual. r22: LDS staging + swizzle. r31: N-loop with
// B register-prefetch (T14) — grid (64,4,4)->(32,4,4); each block stages A
// once, loops 2 N-tiles; B(1) loads issue under compute of tile 0.
// ---------------------------------------------------------------------------
__global__ __launch_bounds__(256) void proj_kernel(const u16* __restrict__ projw,
                                                   const float* __restrict__ projb,
                                                   const u16* __restrict__ ht,
                                                   const float* __restrict__ x,
                                                   float* __restrict__ out) {
  const int nseg = blockIdx.x, mblk = blockIdx.y, b = blockIdx.z;
  const int tid = threadIdx.x;
  const int w = tid >> 6, l = tid & 63, quad = l >> 4, col = l & 15;
  const int m0 = mblk * 64 + w * 16;
  __shared__ __align__(16) u16 als[64 * 256];   // 32 KiB
  __shared__ __align__(16) u16 bls[64 * 256];   // 32 KiB
  // prefetch B(0) into regs; stage A to LDS (A latency overlaps B loads)
  bf16x8 br[2][8];
  {
    const u16* bsrc = ht + (size_t)b * (kN * kC) + (size_t)(nseg * 128) * kC;
#pragma unroll
    for (int p = 0; p < 8; ++p)
      br[0][p] = ldb8(bsrc + (size_t)(p * 256 + tid) * 8);
  }
  {
    const u16* asrc = projw + (size_t)(mblk * 64) * kC;
#pragma unroll
    for (int p = 0; p < 8; ++p) {
      const int li = p * 256 + tid;
      const int row = li >> 5, ch = li & 31;
      const int sw = (ch ^ (row & 7)) * 8;
      *reinterpret_cast<bf16x8*>(&als[row * 256 + sw]) = ldb8(asrc + li * 8);
    }
  }
  const int kx = col & 7;
#pragma unroll
  for (int i = 0; i < 2; ++i) {
    const int n0 = (nseg * 2 + i) * 64;
    // ds_write B(i) from regs
#pragma unroll
    for (int p = 0; p < 8; ++p) {
      const int li = p * 256 + tid;
      const int row = li >> 5, ch = li & 31;
      const int sw = (ch ^ (row & 7)) * 8;
      *reinterpret_cast<bf16x8*>(&bls[row * 256 + sw]) = br[i][p];
    }
    __syncthreads();
    if (i == 0) {
      const u16* bsrc = ht + (size_t)b * (kN * kC) + (size_t)(nseg * 128 + 64) * kC;
#pragma unroll
      for (int p = 0; p < 8; ++p)
        br[1][p] = ldb8(bsrc + (size_t)(p * 256 + tid) * 8);
    }
    f32x4 acc[4] = {{0,0,0,0},{0,0,0,0},{0,0,0,0},{0,0,0,0}};
    const u16* arow = &als[(w * 16 + col) * 256];
#pragma unroll
    for (int ks = 0; ks < 8; ++ks) {
      const bf16x8 af = ldb8(arow + (((ks * 4 + quad) ^ kx)) * 8);
#pragma unroll
      for (int nt = 0; nt < 4; ++nt) {
        const bf16x8 bfr =
            ldb8(&bls[(nt * 16 + col) * 256 + (((ks * 4 + quad) ^ kx)) * 8]);
        acc[nt] = MFMA16x16x32(af, bfr, acc[nt]);
      }
    }
#pragma unroll
    for (int nt = 0; nt < 4; ++nt) {
      const int t = n0 + nt * 16 + col;
#pragma unroll
      for (int r = 0; r < 4; ++r) {
        const int o = m0 + quad * 4 + r;
        const int idx = b * (kC * kN) + o * kN + t;
        out[idx] = acc[nt][r] + projb[o] + x[idx];
      }
    }
    __syncthreads();   // protect bls before next tile overwrites it
  }
}

extern "C" void kernel_launch(void* const* d_in, const int* in_sizes, int n_in,
                              void* d_out, int out_size, void* d_ws, size_t ws_size,
                              hipStream_t stream) {
  const float* x = (const float*)d_in[0];
  const float* gnw = (const float*)d_in[1];
  const float* gnb = (const float*)d_in[2];
  const float* qkvw_f = (const float*)d_in[3];
  const float* qkvb = (const float*)d_in[4];
  const float* projw_f = (const float*)d_in[5];
  const float* projb = (const float*)d_in[6];
  float* out = (float*)d_out;

  char* ws = (char*)d_ws;
  u16* xnT = (u16*)(ws);                      // 8 MiB
  u16* qt = (u16*)(ws + (8u << 20));          // 8 MiB
  u16* kt = (u16*)(ws + (16u << 20));         // 8 MiB
  u16* vv = (u16*)(ws + (24u << 20));         // 8 MiB
  u16* ht = (u16*)(ws + (32u << 20));         // 8 MiB
  u16* qkvw = (u16*)(ws + (40u << 20));       // 384 KiB
  u16* projw = (u16*)(ws + (41u << 20));      // 128 KiB

  convert_bf16_2<<<dim3(256), dim3(256), 0, stream>>>(qkvw_f, qkvw, 768 * kC,
                                                      projw_f, projw, kC * kC);
  gn_kernel<<<dim3(32, 4), dim3(1024), 0, stream>>>(x, gnw, gnb, xnT);
  qkv_gemm<<<dim3(64, 3, 4), dim3(256), 0, stream>>>(qkvw, qkvb, xnT, qt, kt, vv);
  attn_split<<<dim3(512), dim3(512), 0, stream>>>(qt, kt, vv, ht);
  proj_kernel<<<dim3(32, 4, 4), dim3(256), 0, stream>>>(projw, projb, ht, x, out);
}

// Round 19
// 184.153 us; speedup vs baseline: 1.0766x; 1.0079x over previous
//
#include <hip/hip_runtime.h>

typedef unsigned short u16;
typedef unsigned int u32;
typedef __bf16 bf16x8 __attribute__((ext_vector_type(8)));
typedef float f32x4 __attribute__((ext_vector_type(4)));
typedef u16 u16x4 __attribute__((ext_vector_type(4)));
typedef u16 u16x8 __attribute__((ext_vector_type(8)));

#define MFMA16x16x32(a, b, c) __builtin_amdgcn_mfma_f32_16x16x32_bf16((a), (b), (c), 0, 0, 0)

static constexpr int kB = 4;
static constexpr int kC = 256;
static constexpr int kN = 4096;     // H*W
static constexpr int kHeads = 4;    // per batch
static constexpr int kD = 64;       // head dim
static constexpr float kScale = 0.35355339059327373f;   // 64^-0.25 (K side)
static constexpr float kScaleQ = 0.51006971545f;        // 64^-0.25 * log2(e) (Q side)

__device__ __forceinline__ u16 f2bf(float f) {
  union { float f; u32 i; } v; v.f = f;
  return (u16)((v.i + 0x7fffu + ((v.i >> 16) & 1u)) >> 16);
}
__device__ __forceinline__ bf16x8 ldb8(const u16* p) {
  return *reinterpret_cast<const bf16x8*>(p);
}
// r21 (validated): raw v_exp_f32 (2^x); OCML exp2f carries fixup VALU.
__device__ __forceinline__ float fast_exp2(float x) {
#if __has_builtin(__builtin_amdgcn_exp2f)
  return __builtin_amdgcn_exp2f(x);
#else
  float r;
  asm("v_exp_f32 %0, %1" : "=v"(r) : "v"(x));
  return r;
#endif
}

// ---------------------------------------------------------------------------
// Standalone weight conversion (validated r24/r30 form).
// ---------------------------------------------------------------------------
__global__ void convert_bf16_2(const float* __restrict__ in1, u16* __restrict__ out1,
                               int n1, const float* __restrict__ in2,
                               u16* __restrict__ out2, int n2) {
  const int total = n1 + n2;
  for (int i = blockIdx.x * blockDim.x + threadIdx.x; i < total;
       i += gridDim.x * blockDim.x) {
    if (i < n1) out1[i] = f2bf(in1[i]);
    else out2[i - n1] = f2bf(in2[i - n1]);
  }
}

// ---------------------------------------------------------------------------
// GroupNorm (validated r4). Writes bf16 transposed xnT[b][t][c].
// ---------------------------------------------------------------------------
__global__ __launch_bounds__(1024) void gn_kernel(const float* __restrict__ x,
                                                  const float* __restrict__ gnw,
                                                  const float* __restrict__ gnb,
                                                  u16* __restrict__ xnT) {
  const int g = blockIdx.x, b = blockIdx.y;
  const int tid = threadIdx.x;
  const float* xb = x + b * (kC * kN) + g * 8 * kN;
  float vals[4][8];
  float s = 0.f, ss = 0.f;
#pragma unroll
  for (int kk = 0; kk < 4; ++kk) {
    const int t = tid + kk * 1024;
#pragma unroll
    for (int c = 0; c < 8; ++c) {
      const float v_ = xb[c * kN + t];
      vals[kk][c] = v_;
      s += v_; ss += v_ * v_;
    }
  }
#pragma unroll
  for (int off = 32; off > 0; off >>= 1) {
    s += __shfl_down(s, off);
    ss += __shfl_down(ss, off);
  }
  __shared__ float rbuf[32];
  const int wid = tid >> 6, lane = tid & 63;
  if (lane == 0) { rbuf[wid] = s; rbuf[16 + wid] = ss; }
  __syncthreads();
  if (tid < 64) {
    float s2 = (lane < 16) ? rbuf[lane] : 0.f;
    float ss2 = (lane < 16) ? rbuf[16 + lane] : 0.f;
#pragma unroll
    for (int off = 8; off > 0; off >>= 1) {
      s2 += __shfl_down(s2, off);
      ss2 += __shfl_down(ss2, off);
    }
    if (lane == 0) { rbuf[0] = s2; rbuf[1] = ss2; }
  }
  __syncthreads();
  const float inv_n = 1.f / 32768.f;
  const float mu = rbuf[0] * inv_n;
  const float var = rbuf[1] * inv_n - mu * mu;
  const float rs = rsqrtf(var + 1e-5f);
  float wv[8], bv[8];
#pragma unroll
  for (int c = 0; c < 8; ++c) {
    const float wgt = gnw[g * 8 + c] * rs;
    wv[c] = wgt;
    bv[c] = gnb[g * 8 + c] - mu * wgt;
  }
  u16* ob = xnT + b * (kN * kC) + g * 8;
#pragma unroll
  for (int kk = 0; kk < 4; ++kk) {
    const int t = tid + kk * 1024;
    u16x8 pk;
#pragma unroll
    for (int c = 0; c < 8; ++c) pk[c] = f2bf(vals[kk][c] * wv[c] + bv[c]);
    *reinterpret_cast<u16x8*>(ob + t * kC) = pk;
  }
}

// ---------------------------------------------------------------------------
// QKV GEMM. r22: LDS staging + XOR swizzle. r28: M-loop (B staged once).
// r31 (validated): T14 register-prefetch across the m-loop.
// Epilogue: r19 V slot-permutation m = 8*(col>>2)+4*(nt&1)+(col&3); Q side
// folds log2e.
// ---------------------------------------------------------------------------
__global__ __launch_bounds__(256) void qkv_gemm(const u16* __restrict__ qkvw,
                                                const float* __restrict__ qkvb,
                                                const u16* __restrict__ xnT,
                                                u16* __restrict__ qt,
                                                u16* __restrict__ kt,
                                                u16* __restrict__ vv) {
  const int nblk = blockIdx.x, mseg = blockIdx.y, b = blockIdx.z;
  const int tid = threadIdx.x;
  const int w = tid >> 6, l = tid & 63, quad = l >> 4, col = l & 15;
  const int n0 = nblk * 64;
  __shared__ __align__(16) u16 als[64 * 256];   // 32 KiB (A tile, reused)
  __shared__ __align__(16) u16 bls[64 * 256];   // 32 KiB (B panel, once)
  // prefetch A(0) into regs (latency overlaps B staging below)
  bf16x8 ar[2][8];
  {
    const u16* asrc = qkvw + (size_t)(mseg * 4 * 64) * kC;
#pragma unroll
    for (int p = 0; p < 8; ++p)
      ar[0][p] = ldb8(asrc + (size_t)(p * 256 + tid) * 8);
  }
  {
    const u16* bsrc = xnT + (size_t)b * (kN * kC) + (size_t)n0 * kC;
#pragma unroll
    for (int p = 0; p < 8; ++p) {
      const int li = p * 256 + tid;        // [0,2048)
      const int row = li >> 5, ch = li & 31;
      const int sw = (ch ^ (row & 7)) * 8;
      *reinterpret_cast<bf16x8*>(&bls[row * 256 + sw]) = ldb8(bsrc + li * 8);
    }
  }
  const int kx = col & 7;
#pragma unroll
  for (int msub = 0; msub < 4; ++msub) {
    const int cur = msub & 1, nxt = cur ^ 1;
    const int mblk = mseg * 4 + msub;
    const int m0 = mblk * 64 + w * 16;
    // ds_write A(msub) from regs
#pragma unroll
    for (int p = 0; p < 8; ++p) {
      const int li = p * 256 + tid;
      const int row = li >> 5, ch = li & 31;
      const int sw = (ch ^ (row & 7)) * 8;
      *reinterpret_cast<bf16x8*>(&als[row * 256 + sw]) = ar[cur][p];
    }
    __syncthreads();
    // issue A(msub+1) loads; latency hidden under compute+epilogue
    if (msub < 3) {
      const u16* asrc = qkvw + (size_t)((mblk + 1) * 64) * kC;
#pragma unroll
      for (int p = 0; p < 8; ++p)
        ar[nxt][p] = ldb8(asrc + (size_t)(p * 256 + tid) * 8);
    }
    f32x4 acc[4] = {{0,0,0,0},{0,0,0,0},{0,0,0,0},{0,0,0,0}};
    const u16* arow = &als[(w * 16 + col) * 256];
#pragma unroll
    for (int ks = 0; ks < 8; ++ks) {
      const bf16x8 af = ldb8(arow + (((ks * 4 + quad) ^ kx)) * 8);
#pragma unroll
      for (int nt = 0; nt < 4; ++nt) {
        const bf16x8 bfr =
            ldb8(&bls[(nt * 16 + col) * 256 + (((ks * 4 + quad) ^ kx)) * 8]);
        acc[nt] = MFMA16x16x32(af, bfr, acc[nt]);
      }
    }
    const int o_base = m0 + quad * 4;
    const int head = o_base / 192;
    const int rr = o_base % 192;
    const int bh = b * kHeads + head;
    const int seg = rr >> 6;
    const int c0 = rr & 63;
    float bias[4];
#pragma unroll
    for (int r = 0; r < 4; ++r) bias[r] = qkvb[o_base + r];
    const float sc = (seg == 0) ? kScaleQ : kScale;
#pragma unroll
    for (int nt = 0; nt < 4; ++nt) {
      const int t = n0 + nt * 16 + col;
      if (seg == 2) {
        const int tp = n0 + (nt >> 1) * 32 + 8 * (col >> 2) + 4 * (nt & 1) + (col & 3);
#pragma unroll
        for (int r = 0; r < 4; ++r)
          vv[bh * (kD * kN) + (c0 + r) * kN + tp] = f2bf(acc[nt][r] + bias[r]);
      } else {
        u16* dst = (seg == 0 ? qt : kt) + bh * (kN * kD) + t * kD + c0;
        u16x4 pk;
#pragma unroll
        for (int r = 0; r < 4; ++r) pk[r] = f2bf((acc[nt][r] + bias[r]) * sc);
        *reinterpret_cast<u16x4*>(dst) = pk;
      }
    }
    __syncthreads();   // protect als before next m-tile overwrites it
  }
}

// ---------------------------------------------------------------------------
// Flash attention, UNSPLIT. Validated ladder: r20 staging, r21 fast_exp2,
// r24 fused combine, r27 4-phase, r28 setprio, r29 XCD remap.
// r32: INTRA-WAVE SOFTWARE PIPELINE. Counters showed MfmaUtil(44)+
// VALUBusy(40) SUM (pipes alternate, never overlap): the per-phase chain
// QK -> exp(dep) -> PV(dep) drains the MFMA pipe before every exp. Fix:
// one-phase lookahead — issue QK(h+1) MFMAs BEFORE exp/pack(h), so exp(h)
// VALU issue overlaps QK(h+1) MFMA execution. Same math, reordered only;
// all indices compile-time (rule #20); no addr recompute (r17 avoided).
// Lookahead covers h=0..2 (no cross-iteration crossing).
// ---------------------------------------------------------------------------
__global__ __launch_bounds__(512, 4) void attn_split(const u16* __restrict__ qt,
                                                     const u16* __restrict__ kt,
                                                     const u16* __restrict__ vv,
                                                     u16* __restrict__ ht) {
  const int bid = blockIdx.x;
  const int xcd = bid & 7, j = bid >> 3;
  const int bh = (xcd << 1) | (j >> 5);
  const int tblk = j & 31;
  const int tid = threadIdx.x;
  const int w = tid >> 6, l = tid & 63, quad = l >> 4, col = l & 15;
  const int t0 = tblk * 128 + w * 16;          // 8 waves x 16 q-rows
  const u16* qb = qt + bh * (kN * kD);
  const u16* kb = kt + bh * (kN * kD);
  const u16* vb = vv + bh * (kD * kN);
  bf16x8 qf0, qf1;
  qf0 = ldb8(qb + (t0 + col) * kD + quad * 8);
  qf1 = ldb8(qb + (t0 + col) * kD + 32 + quad * 8);
  u16x8 ones_u;
#pragma unroll
  for (int i = 0; i < 8; ++i) ones_u[i] = 0x3f80;  // bf16 1.0
  const bf16x8 onesf = *reinterpret_cast<bf16x8*>(&ones_u);
  f32x4 oacc[4];
  f32x4 lacc = {0, 0, 0, 0};
#pragma unroll
  for (int ct = 0; ct < 4; ++ct) oacc[ct] = f32x4{0, 0, 0, 0};

  __shared__ __align__(16) u16 kls[2][4][32][64];   // 32 KiB: [buf][half]
  __shared__ __align__(16) u16 vls[2][4][32][64];   // 32 KiB
  constexpr int NIT = kN / 128;                      // 32
  constexpr int BUFSTRIDE = 4 * 32 * 64;             // 8192 u16

  // --- staging roles: 512 threads, 2 K-chunks + 2 V-chunks of 16B each ---
  const int r6 = tid >> 3, c3 = tid & 7;             // K chunk 0: row r6
  const u16* ksrc = kb + (size_t)r6 * kD + c3 * 8;   // chunk 1: +64 rows
  u16* kdst = &kls[0][r6 >> 5][r6 & 31][(c3 ^ (r6 & 7)) * 8];
  // V chunk 0: id=tid (half vh, row vr, chunk vc3); chunk 1: id+512 (half+2)
  const int vh = tid >> 8, vcc = tid & 255, vr = vcc >> 3, vc3 = vcc & 7;
  const int sa = vc3 >> 2, sq = vc3 & 3;
  const u16* vsrc = vb + (size_t)(2 * vr + sa) * kN + vh * 32 + sq * 8;
  u16* vdst = &vls[0][vh][vr][(((sa << 2) | sq) ^ (vr & 7)) * 8];

  // prologue: load tile 0 (4 chunks)
  bf16x8 kstg0 = ldb8(ksrc);
  bf16x8 kstg1 = ldb8(ksrc + (size_t)64 * kD);
  bf16x8 vstg0 = ldb8(vsrc);
  bf16x8 vstg1 = ldb8(vsrc + 64);

#pragma unroll 2
  for (int it = 0; it < NIT; ++it) {
    const int cb = (it & 1) * BUFSTRIDE;
    *reinterpret_cast<bf16x8*>(kdst + cb) = kstg0;
    *reinterpret_cast<bf16x8*>(kdst + cb + 2 * 2048) = kstg1;
    *reinterpret_cast<bf16x8*>(vdst + cb) = vstg0;
    *reinterpret_cast<bf16x8*>(vdst + cb + 2 * 2048) = vstg1;
    __syncthreads();
    if (it + 1 < NIT) {
      const size_t sb = (size_t)(it + 1) * 128;
      kstg0 = ldb8(ksrc + sb * kD);
      kstg1 = ldb8(ksrc + (sb + 64) * kD);
      vstg0 = ldb8(vsrc + sb);
      vstg1 = ldb8(vsrc + sb + 64);
    }
    const int kx = (col & 7) * 8;
    const int vslot = (((col & 1) << 2) | quad) ^ (col >> 1);
    // pipeline state: S-rows for phase h live in sA0[h]/sA1[h]
    f32x4 sA0[4], sA1[4];
    // prologue: QK(0)
    {
      const u16* kl = &kls[0][0][0][0] + cb;
      const bf16x8 k00 = ldb8(kl + col * 64 + ((quad * 8) ^ kx));
      const bf16x8 k01 = ldb8(kl + col * 64 + ((32 + quad * 8) ^ kx));
      const bf16x8 k10 = ldb8(kl + (col + 16) * 64 + ((quad * 8) ^ kx));
      const bf16x8 k11 = ldb8(kl + (col + 16) * 64 + ((32 + quad * 8) ^ kx));
      f32x4 a0 = {0, 0, 0, 0}, a1 = {0, 0, 0, 0};
      __builtin_amdgcn_s_setprio(1);
      a0 = MFMA16x16x32(k00, qf0, a0);
      a0 = MFMA16x16x32(k01, qf1, a0);
      a1 = MFMA16x16x32(k10, qf0, a1);
      a1 = MFMA16x16x32(k11, qf1, a1);
      __builtin_amdgcn_s_setprio(0);
      sA0[0] = a0; sA1[0] = a1;
    }
#pragma unroll
    for (int h = 0; h < 4; ++h) {
      // lookahead: issue QK(h+1) BEFORE exp/pack(h) so the exp VALU
      // overlaps these MFMAs' execution.
      if (h < 3) {
        const u16* kl = &kls[0][0][0][0] + cb + (h + 1) * 2048;
        const bf16x8 k00 = ldb8(kl + col * 64 + ((quad * 8) ^ kx));
        const bf16x8 k01 = ldb8(kl + col * 64 + ((32 + quad * 8) ^ kx));
        const bf16x8 k10 = ldb8(kl + (col + 16) * 64 + ((quad * 8) ^ kx));
        const bf16x8 k11 = ldb8(kl + (col + 16) * 64 + ((32 + quad * 8) ^ kx));
        f32x4 a0 = {0, 0, 0, 0}, a1 = {0, 0, 0, 0};
        __builtin_amdgcn_s_setprio(1);
        a0 = MFMA16x16x32(k00, qf0, a0);
        a0 = MFMA16x16x32(k01, qf1, a0);
        a1 = MFMA16x16x32(k10, qf0, a1);
        a1 = MFMA16x16x32(k11, qf1, a1);
        __builtin_amdgcn_s_setprio(0);
        sA0[h + 1] = a0; sA1[h + 1] = a1;
      }
      // exp/pack(h) — depends only on sA(h), ready since last phase
      const u32 e00 = __float_as_uint(fast_exp2(sA0[h][0]));
      const u32 e01 = __float_as_uint(fast_exp2(sA0[h][1]));
      const u32 e02 = __float_as_uint(fast_exp2(sA0[h][2]));
      const u32 e03 = __float_as_uint(fast_exp2(sA0[h][3]));
      const u32 e10 = __float_as_uint(fast_exp2(sA1[h][0]));
      const u32 e11 = __float_as_uint(fast_exp2(sA1[h][1]));
      const u32 e12 = __float_as_uint(fast_exp2(sA1[h][2]));
      const u32 e13 = __float_as_uint(fast_exp2(sA1[h][3]));
      union { u32 wd[4]; bf16x8 v; } pa;
      pa.wd[0] = __builtin_amdgcn_perm(e01, e00, 0x07060302u);
      pa.wd[1] = __builtin_amdgcn_perm(e03, e02, 0x07060302u);
      pa.wd[2] = __builtin_amdgcn_perm(e11, e10, 0x07060302u);
      pa.wd[3] = __builtin_amdgcn_perm(e13, e12, 0x07060302u);
      // PV(h)
      const u16* vl = &vls[0][0][0][0] + cb + h * 2048;
      bf16x8 vf[4];
#pragma unroll
      for (int ct = 0; ct < 4; ++ct)
        vf[ct] = ldb8(vl + (ct * 8 + (col >> 1)) * 64 + vslot * 8);
      __builtin_amdgcn_s_setprio(1);
#pragma unroll
      for (int ct = 0; ct < 4; ++ct)
        oacc[ct] = MFMA16x16x32(pa.v, vf[ct], oacc[ct]);
      lacc = MFMA16x16x32(pa.v, onesf, lacc);
      __builtin_amdgcn_s_setprio(0);
    }
  }
  // epilogue: divide by l (every col holds l[q]) and write ht bf16 directly
  const int b = bh >> 2, head = bh & 3;
  u16* hb = ht + (size_t)b * (kN * kC) + head * kD;
#pragma unroll
  for (int r = 0; r < 4; ++r) {
    const int t = t0 + quad * 4 + r;
    const float inv = 1.f / lacc[r];
#pragma unroll
    for (int ct = 0; ct < 4; ++ct)
      hb[(size_t)t * kC + ct * 16 + col] = f2bf(oacc[ct][r] * inv);
  }
}

// ---------------------------------------------------------------------------
// Proj GEMM + bias + residual. r22: LDS staging + swizzle. r31 (validated):
// N-loop with B register-prefetch (T14).
// ---------------------------------------------------------------------------
__global__ __launch_bounds__(256) void proj_kernel(const u16* __restrict__ projw,
                                                   const float* __restrict__ projb,
                                                   const u16* __restrict__ ht,
                                                   const float* __restrict__ x,
                                                   float* __restrict__ out) {
  const int nseg = blockIdx.x, mblk = blockIdx.y, b = blockIdx.z;
  const int tid = threadIdx.x;
  const int w = tid >> 6, l = tid & 63, quad = l >> 4, col = l & 15;
  const int m0 = mblk * 64 + w * 16;
  __shared__ __align__(16) u16 als[64 * 256];   // 32 KiB
  __shared__ __align__(16) u16 bls[64 * 256];   // 32 KiB
  // prefetch B(0) into regs; stage A to LDS (A latency overlaps B loads)
  bf16x8 br[2][8];
  {
    const u16* bsrc = ht + (size_t)b * (kN * kC) + (size_t)(nseg * 128) * kC;
#pragma unroll
    for (int p = 0; p < 8; ++p)
      br[0][p] = ldb8(bsrc + (size_t)(p * 256 + tid) * 8);
  }
  {
    const u16* asrc = projw + (size_t)(mblk * 64) * kC;
#pragma unroll
    for (int p = 0; p < 8; ++p) {
      const int li = p * 256 + tid;
      const int row = li >> 5, ch = li & 31;
      const int sw = (ch ^ (row & 7)) * 8;
      *reinterpret_cast<bf16x8*>(&als[row * 256 + sw]) = ldb8(asrc + li * 8);
    }
  }
  const int kx = col & 7;
#pragma unroll
  for (int i = 0; i < 2; ++i) {
    const int n0 = (nseg * 2 + i) * 64;
    // ds_write B(i) from regs
#pragma unroll
    for (int p = 0; p < 8; ++p) {
      const int li = p * 256 + tid;
      const int row = li >> 5, ch = li & 31;
      const int sw = (ch ^ (row & 7)) * 8;
      *reinterpret_cast<bf16x8*>(&bls[row * 256 + sw]) = br[i][p];
    }
    __syncthreads();
    if (i == 0) {
      const u16* bsrc = ht + (size_t)b * (kN * kC) + (size_t)(nseg * 128 + 64) * kC;
#pragma unroll
      for (int p = 0; p < 8; ++p)
        br[1][p] = ldb8(bsrc + (size_t)(p * 256 + tid) * 8);
    }
    f32x4 acc[4] = {{0,0,0,0},{0,0,0,0},{0,0,0,0},{0,0,0,0}};
    const u16* arow = &als[(w * 16 + col) * 256];
#pragma unroll
    for (int ks = 0; ks < 8; ++ks) {
      const bf16x8 af = ldb8(arow + (((ks * 4 + quad) ^ kx)) * 8);
#pragma unroll
      for (int nt = 0; nt < 4; ++nt) {
        const bf16x8 bfr =
            ldb8(&bls[(nt * 16 + col) * 256 + (((ks * 4 + quad) ^ kx)) * 8]);
        acc[nt] = MFMA16x16x32(af, bfr, acc[nt]);
      }
    }
#pragma unroll
    for (int nt = 0; nt < 4; ++nt) {
      const int t = n0 + nt * 16 + col;
#pragma unroll
      for (int r = 0; r < 4; ++r) {
        const int o = m0 + quad * 4 + r;
        const int idx = b * (kC * kN) + o * kN + t;
        out[idx] = acc[nt][r] + projb[o] + x[idx];
      }
    }
    __syncthreads();   // protect bls before next tile overwrites it
  }
}

extern "C" void kernel_launch(void* const* d_in, const int* in_sizes, int n_in,
                              void* d_out, int out_size, void* d_ws, size_t ws_size,
                              hipStream_t stream) {
  const float* x = (const float*)d_in[0];
  const float* gnw = (const float*)d_in[1];
  const float* gnb = (const float*)d_in[2];
  const float* qkvw_f = (const float*)d_in[3];
  const float* qkvb = (const float*)d_in[4];
  const float* projw_f = (const float*)d_in[5];
  const float* projb = (const float*)d_in[6];
  float* out = (float*)d_out;

  char* ws = (char*)d_ws;
  u16* xnT = (u16*)(ws);                      // 8 MiB
  u16* qt = (u16*)(ws + (8u << 20));          // 8 MiB
  u16* kt = (u16*)(ws + (16u << 20));         // 8 MiB
  u16* vv = (u16*)(ws + (24u << 20));         // 8 MiB
  u16* ht = (u16*)(ws + (32u << 20));         // 8 MiB
  u16* qkvw = (u16*)(ws + (40u << 20));       // 384 KiB
  u16* projw = (u16*)(ws + (41u << 20));      // 128 KiB

  convert_bf16_2<<<dim3(256), dim3(256), 0, stream>>>(qkvw_f, qkvw, 768 * kC,
                                                      projw_f, projw, kC * kC);
  gn_kernel<<<dim3(32, 4), dim3(1024), 0, stream>>>(x, gnw, gnb, xnT);
  qkv_gemm<<<dim3(64, 3, 4), dim3(256), 0, stream>>>(qkvw, qkvb, xnT, qt, kt, vv);
  attn_split<<<dim3(512), dim3(512), 0, stream>>>(qt, kt, vv, ht);
  proj_kernel<<<dim3(32, 4, 4), dim3(256), 0, stream>>>(projw, projb, ht, x, out);
}